// Round 5
// baseline (218.914 us; speedup 1.0000x reference)
//
#include <hip/hip_runtime.h>

// out[row] = x[row] - sum(x[row])  for rows of D=512 fp32 (65536 rows).
// One wave (64 lanes) handles FOUR consecutive rows: 8 independent 16B
// loads issued up-front (128B/lane in flight), four interleaved 64-lane
// shfl_xor butterflies (ILP), nontemporal vector loads+stores (streaming).

#define D 512
#define WAVES_PER_BLOCK 4
#define BLOCK (WAVES_PER_BLOCK * 64)
#define ROWS_PER_WAVE 4

typedef float v4f __attribute__((ext_vector_type(4)));

__global__ __launch_bounds__(BLOCK) void rowsub4_kernel(const float* __restrict__ x,
                                                        float* __restrict__ out,
                                                        int nquads) {
    const int wave = threadIdx.x >> 6;   // 0..3
    const int lane = threadIdx.x & 63;   // 0..63
    const long long quad = (long long)blockIdx.x * WAVES_PER_BLOCK + wave;
    if (quad >= nquads) return;

    // Four consecutive rows = 2048 contiguous floats = 512 v4f.
    const v4f* __restrict__ xr = reinterpret_cast<const v4f*>(x + quad * (ROWS_PER_WAVE * D));
    v4f* __restrict__ orow     = reinterpret_cast<v4f*>(out + quad * (ROWS_PER_WAVE * D));

    // Issue all 8 loads before any dependent arithmetic.
    v4f a0 = __builtin_nontemporal_load(&xr[lane]);
    v4f a1 = __builtin_nontemporal_load(&xr[lane + 64]);
    v4f b0 = __builtin_nontemporal_load(&xr[lane + 128]);
    v4f b1 = __builtin_nontemporal_load(&xr[lane + 192]);
    v4f c0 = __builtin_nontemporal_load(&xr[lane + 256]);
    v4f c1 = __builtin_nontemporal_load(&xr[lane + 320]);
    v4f e0 = __builtin_nontemporal_load(&xr[lane + 384]);
    v4f e1 = __builtin_nontemporal_load(&xr[lane + 448]);

    float s0 = (a0.x + a0.y) + (a0.z + a0.w) + (a1.x + a1.y) + (a1.z + a1.w);
    float s1 = (b0.x + b0.y) + (b0.z + b0.w) + (b1.x + b1.y) + (b1.z + b1.w);
    float s2 = (c0.x + c0.y) + (c0.z + c0.w) + (c1.x + c1.y) + (c1.z + c1.w);
    float s3 = (e0.x + e0.y) + (e0.z + e0.w) + (e1.x + e1.y) + (e1.z + e1.w);

    // Four independent 64-lane butterflies — interleaved for ILP.
    #pragma unroll
    for (int off = 32; off > 0; off >>= 1) {
        s0 += __shfl_xor(s0, off, 64);
        s1 += __shfl_xor(s1, off, 64);
        s2 += __shfl_xor(s2, off, 64);
        s3 += __shfl_xor(s3, off, 64);
    }

    __builtin_nontemporal_store(a0 - s0, &orow[lane]);
    __builtin_nontemporal_store(a1 - s0, &orow[lane + 64]);
    __builtin_nontemporal_store(b0 - s1, &orow[lane + 128]);
    __builtin_nontemporal_store(b1 - s1, &orow[lane + 192]);
    __builtin_nontemporal_store(c0 - s2, &orow[lane + 256]);
    __builtin_nontemporal_store(c1 - s2, &orow[lane + 320]);
    __builtin_nontemporal_store(e0 - s3, &orow[lane + 384]);
    __builtin_nontemporal_store(e1 - s3, &orow[lane + 448]);
}

extern "C" void kernel_launch(void* const* d_in, const int* in_sizes, int n_in,
                              void* d_out, int out_size, void* d_ws, size_t ws_size,
                              hipStream_t stream) {
    const float* x = (const float*)d_in[0];
    float* out = (float*)d_out;
    const int nrows = in_sizes[0] / D;                 // 65536
    const int nquads = nrows / ROWS_PER_WAVE;          // 16384 (rows divisible by 4)
    const int grid = (nquads + WAVES_PER_BLOCK - 1) / WAVES_PER_BLOCK;
    rowsub4_kernel<<<grid, BLOCK, 0, stream>>>(x, out, nquads);
}

// Round 6
// 218.361 us; speedup vs baseline: 1.0025x; 1.0025x over previous
//
#include <hip/hip_runtime.h>

// out[row] = x[row] - sum(x[row])  for rows of D=512 fp32 (65536 rows).
// Persistent grid-stride kernel, 2 rows (1 "pair") per wave per iteration,
// software-pipelined: next pair's 4x16B loads are issued BEFORE the current
// pair's shuffle-reduce + NT stores, so the 6-step shfl chain and the store
// burst always overlap with outstanding loads. 8192 waves x 4 pairs each.

#define D 512
#define BLOCK 256
#define WPB (BLOCK / 64)

typedef float v4f __attribute__((ext_vector_type(4)));

__global__ __launch_bounds__(BLOCK) void rowsub_pipe_kernel(const float* __restrict__ x,
                                                            float* __restrict__ out,
                                                            int npairs) {
    const int lane  = threadIdx.x & 63;
    const int gwave = blockIdx.x * WPB + (threadIdx.x >> 6);
    const int nwaves = gridDim.x * WPB;

    long long p = gwave;
    if (p >= npairs) return;

    // One pair = 2 rows = 1024 floats = 256 v4f.
    const v4f* __restrict__ xb = reinterpret_cast<const v4f*>(x);
    v4f* __restrict__ ob       = reinterpret_cast<v4f*>(out);

    const v4f* xr = xb + p * 256;
    v4f a0 = __builtin_nontemporal_load(&xr[lane]);
    v4f a1 = __builtin_nontemporal_load(&xr[lane + 64]);
    v4f b0 = __builtin_nontemporal_load(&xr[lane + 128]);
    v4f b1 = __builtin_nontemporal_load(&xr[lane + 192]);

    while (true) {
        const long long pn = p + nwaves;
        const bool more = (pn < npairs);
        v4f c0, c1, e0, e1;
        if (more) {
            const v4f* xn = xb + pn * 256;
            c0 = __builtin_nontemporal_load(&xn[lane]);
            c1 = __builtin_nontemporal_load(&xn[lane + 64]);
            e0 = __builtin_nontemporal_load(&xn[lane + 128]);
            e1 = __builtin_nontemporal_load(&xn[lane + 192]);
        }

        float s0 = (a0.x + a0.y) + (a0.z + a0.w) + (a1.x + a1.y) + (a1.z + a1.w);
        float s1 = (b0.x + b0.y) + (b0.z + b0.w) + (b1.x + b1.y) + (b1.z + b1.w);
        #pragma unroll
        for (int off = 32; off > 0; off >>= 1) {
            s0 += __shfl_xor(s0, off, 64);
            s1 += __shfl_xor(s1, off, 64);
        }

        v4f* orow = ob + p * 256;
        __builtin_nontemporal_store(a0 - s0, &orow[lane]);
        __builtin_nontemporal_store(a1 - s0, &orow[lane + 64]);
        __builtin_nontemporal_store(b0 - s1, &orow[lane + 128]);
        __builtin_nontemporal_store(b1 - s1, &orow[lane + 192]);

        if (!more) break;
        a0 = c0; a1 = c1; b0 = e0; b1 = e1;
        p = pn;
    }
}

extern "C" void kernel_launch(void* const* d_in, const int* in_sizes, int n_in,
                              void* d_out, int out_size, void* d_ws, size_t ws_size,
                              hipStream_t stream) {
    const float* x = (const float*)d_in[0];
    float* out = (float*)d_out;
    const int nrows  = in_sizes[0] / D;   // 65536
    const int npairs = nrows / 2;         // 32768
    // 2048 blocks = 8192 waves -> exactly 4 pairs per wave (32768/8192),
    // uniform trip count, full pipeline benefit on 3 of 4 iterations.
    const int grid = 2048;
    rowsub_pipe_kernel<<<grid, BLOCK, 0, stream>>>(x, out, npairs);
}